// Round 9
// baseline (233.332 us; speedup 1.0000x reference)
//
#include <hip/hip_runtime.h>
#include <hip/hip_fp16.h>

#define BATCH 256
#define ICAPS 1152
#define OCAPS 10
#define OD    160
#define BLOCK 768            // 12 waves, 1 block/CU (LDS-bound), 256 blocks = 256 CUs
#define NW    12
#define NPAIR 384            // lane pairs; pair P owns rows P, P+384 (regs), 768+P (LDS)

// Fully on-chip dynamic routing: x_b (fp16, 369 KB) lives in VGPRs (rows 0..767,
// 80 regs/thread) + LDS (rows 768..1151, chunk-major -> lane-contiguous ds ops).
// Even lane of a pair owns d 0..79 (o 0..4), odd lane d 80..159 (o 5..9), so
// dots are lane-local; softmax needs one shfl_xor(1) 5-value exchange; weighted
// sums reduce via a 3-level parity-preserving shfl tree into part[12][4][160].
// HBM traffic: one fp32 read of x + 160 KB output. b-state in registers.
__global__ __launch_bounds__(BLOCK) void k_caps(const float* __restrict__ x,
                                                float* __restrict__ out) {
    __shared__ uint4 xl4[20 * NPAIR];           // 122880 B: slot (c*384+P), c=half*10+j
    __shared__ float part[NW][4][OD];           // 30720 B partial col-sums
    __shared__ __align__(16) float v_lds[OD];   // 640 B

    const int b    = blockIdx.x;
    const int t    = threadIdx.x;
    const int w    = t >> 6;
    const int ln   = t & 63;
    const int half = ln & 1;
    const int P    = t >> 1;                    // pair id 0..383

    const float* xp = x + (size_t)b * (ICAPS * OD);

    unsigned xr[2][40];                         // 2 reg rows x 40 half2 words
    float breg[2][5] = {{0,0,0,0,0},{0,0,0,0,0}};
    float bl[5] = {0,0,0,0,0};                  // b-state of the LDS row
    float creg[2][5], cl[5];
    #pragma unroll
    for (int j = 0; j < 5; ++j) { creg[0][j] = 1.f; creg[1][j] = 1.f; cl[j] = 1.f; }

    // ---------- load pass: fp32 -> fp16 into regs + LDS (only HBM read) ----------
    #pragma unroll
    for (int rr = 0; rr < 2; ++rr) {
        const float* bp = xp + (P + rr * NPAIR) * OD + half * 80;
        #pragma unroll
        for (int j = 0; j < 20; ++j) {
            const float4 f = *(const float4*)(bp + j * 4);
            __half2 h0 = __floats2half2_rn(f.x, f.y);
            __half2 h1 = __floats2half2_rn(f.z, f.w);
            xr[rr][j*2]   = *(unsigned*)&h0;
            xr[rr][j*2+1] = *(unsigned*)&h1;
        }
    }
    {
        const float* bp = xp + (768 + P) * OD + half * 80;
        #pragma unroll
        for (int j = 0; j < 10; ++j) {
            const float4 fa = *(const float4*)(bp + j * 8);
            const float4 fb = *(const float4*)(bp + j * 8 + 4);
            __half2 h0 = __floats2half2_rn(fa.x, fa.y);
            __half2 h1 = __floats2half2_rn(fa.z, fa.w);
            __half2 h2 = __floats2half2_rn(fb.x, fb.y);
            __half2 h3 = __floats2half2_rn(fb.z, fb.w);
            uint4 u;
            u.x = *(unsigned*)&h0; u.y = *(unsigned*)&h1;
            u.z = *(unsigned*)&h2; u.w = *(unsigned*)&h3;
            xl4[(half * 10 + j) * NPAIR + P] = u;   // lane-contiguous ds_write_b128
        }
    }
    __syncthreads();

    for (int it = 0; it <= 3; ++it) {
        if (it > 0) {
            // ---------- dot phase: b += <x_row, v>, all lane-local ----------
            #pragma unroll
            for (int ol = 0; ol < 5; ++ol) {
                const int og = half * 5 + ol;
                float wr_[16];
                *(float4*)&wr_[0]  = *(const float4*)&v_lds[og*16+0];
                *(float4*)&wr_[4]  = *(const float4*)&v_lds[og*16+4];
                *(float4*)&wr_[8]  = *(const float4*)&v_lds[og*16+8];
                *(float4*)&wr_[12] = *(const float4*)&v_lds[og*16+12];
                #pragma unroll
                for (int rr = 0; rr < 2; ++rr) {
                    float d = 0.f;
                    #pragma unroll
                    for (int k = 0; k < 8; ++k) {
                        const float2 f = __half22float2(*(const __half2*)&xr[rr][ol*8+k]);
                        d += f.x * wr_[2*k] + f.y * wr_[2*k+1];
                    }
                    breg[rr][ol] += d;
                }
                const uint4 u0 = xl4[(half*10 + ol*2    ) * NPAIR + P];
                const uint4 u1 = xl4[(half*10 + ol*2 + 1) * NPAIR + P];
                unsigned uw[8] = {u0.x,u0.y,u0.z,u0.w,u1.x,u1.y,u1.z,u1.w};
                float dl = 0.f;
                #pragma unroll
                for (int k = 0; k < 8; ++k) {
                    const float2 f = __half22float2(*(const __half2*)&uw[k]);
                    dl += f.x * wr_[2*k] + f.y * wr_[2*k+1];
                }
                bl[ol] += dl;
            }
            // ---------- softmax: exchange 5 logits with partner lane ----------
            #pragma unroll
            for (int rr = 0; rr < 2; ++rr) {
                float oth[5];
                #pragma unroll
                for (int j = 0; j < 5; ++j) oth[j] = __shfl_xor(breg[rr][j], 1, 64);
                float m = breg[rr][0];
                #pragma unroll
                for (int j = 0; j < 5; ++j) { m = fmaxf(m, breg[rr][j]); m = fmaxf(m, oth[j]); }
                float e[5], s = 0.f;
                #pragma unroll
                for (int j = 0; j < 5; ++j) {
                    e[j] = __expf(breg[rr][j] - m); s += e[j];
                    s += __expf(oth[j] - m);
                }
                const float inv = 1.f / s;
                #pragma unroll
                for (int j = 0; j < 5; ++j) creg[rr][j] = e[j] * inv;
            }
            {
                float oth[5];
                #pragma unroll
                for (int j = 0; j < 5; ++j) oth[j] = __shfl_xor(bl[j], 1, 64);
                float m = bl[0];
                #pragma unroll
                for (int j = 0; j < 5; ++j) { m = fmaxf(m, bl[j]); m = fmaxf(m, oth[j]); }
                float e[5], s = 0.f;
                #pragma unroll
                for (int j = 0; j < 5; ++j) {
                    e[j] = __expf(bl[j] - m); s += e[j];
                    s += __expf(oth[j] - m);
                }
                const float inv = 1.f / s;
                #pragma unroll
                for (int j = 0; j < 5; ++j) cl[j] = e[j] * inv;
            }
        }
        // ---------- weighted-sum phase: s = sum_rows c*x (c=1 at it=0) ----------
        #pragma unroll
        for (int ol = 0; ol < 5; ++ol) {
            float acc[16];
            #pragma unroll
            for (int k = 0; k < 16; ++k) acc[k] = 0.f;
            #pragma unroll
            for (int rr = 0; rr < 2; ++rr) {
                const float cc = creg[rr][ol];
                #pragma unroll
                for (int k = 0; k < 8; ++k) {
                    const float2 f = __half22float2(*(const __half2*)&xr[rr][ol*8+k]);
                    acc[2*k]   += cc * f.x;
                    acc[2*k+1] += cc * f.y;
                }
            }
            {
                const uint4 u0 = xl4[(half*10 + ol*2    ) * NPAIR + P];
                const uint4 u1 = xl4[(half*10 + ol*2 + 1) * NPAIR + P];
                unsigned uw[8] = {u0.x,u0.y,u0.z,u0.w,u1.x,u1.y,u1.z,u1.w};
                const float cc = cl[ol];
                #pragma unroll
                for (int k = 0; k < 8; ++k) {
                    const float2 f = __half22float2(*(const __half2*)&uw[k]);
                    acc[2*k]   += cc * f.x;
                    acc[2*k+1] += cc * f.y;
                }
            }
            // parity-preserving tree over strides 2,4,8: 8 partials/wave remain
            #pragma unroll
            for (int mm = 2; mm <= 8; mm <<= 1)
                #pragma unroll
                for (int k = 0; k < 16; ++k) acc[k] += __shfl_xor(acc[k], mm, 64);
            if ((ln & 14) == 0) {               // lanes 0,1,16,17,32,33,48,49
                float* pp = &part[w][ln >> 4][half * 80 + ol * 16];
                #pragma unroll
                for (int k = 0; k < 16; ++k) pp[k] = acc[k];
            }
        }
        __syncthreads();
        // ---------- final reduce over 48 partials + squash ----------
        if (t < OD) {
            float s = 0.f;
            #pragma unroll
            for (int ww = 0; ww < NW; ++ww)
                #pragma unroll
                for (int g = 0; g < 4; ++g) s += part[ww][g][t];
            if (it == 0) s *= 0.1f;
            float sq = s * s;
            #pragma unroll
            for (int mm = 1; mm < 16; mm <<= 1) sq += __shfl_xor(sq, mm, 64);
            const float sc = sqrtf(sq) / (1.f + sq);
            if (it == 3) out[(size_t)b * OD + t] = s * sc;
            else         v_lds[t] = s * sc;
        }
        __syncthreads();
    }
}

extern "C" void kernel_launch(void* const* d_in, const int* in_sizes, int n_in,
                              void* d_out, int out_size, void* d_ws, size_t ws_size,
                              hipStream_t stream) {
    const float* x = (const float*)d_in[0];
    float* vout = (float*)d_out;
    k_caps<<<BATCH, BLOCK, 0, stream>>>(x, vout);
}